// Round 4
// baseline (77.493 us; speedup 1.0000x reference)
//
#include <hip/hip_runtime.h>
#include <hip/hip_bf16.h>

// out[n] = bump( max_l min_f max_c |A[n,l,c] - B[c,f]| ),  bump(x)=sigmoid(10x)*sigmoid(-10x)
// bump strictly decreasing for x>=0  =>  reduce t = max first, bump once at the end.
// N=64, L=512, F=2048.  A:(64,512,2) f32, B:(1,2,2048) f32, out:(64,1) f32.
// Single dispatch: 1024 blocks reduce 32 pairs each -> ws[b]; the LAST block to
// arrive at an atomic counter (seeded by the harness's deterministic 0xAA poison
// of d_ws) does the 16-way max per n + bump + store. Counter test uses mod-1024
// residue so it is correct even across launches without a re-poison.

#define NN 64
#define LL 512
#define FF 2048
#define P  8                      // pairs per wave (lanes stripe f)
#define NBLK ((NN * LL) / 32)     // 1024 blocks, 32 pairs each, 16 blocks per n

__global__ __launch_bounds__(256) void psl_fused_kernel(
    const float* __restrict__ A, const float* __restrict__ B,
    float* __restrict__ out, float* __restrict__ ws,
    unsigned* __restrict__ cnt) {
  const int wave = __builtin_amdgcn_readfirstlane(threadIdx.x >> 6);
  const int lane = threadIdx.x & 63;
  const int p_base = blockIdx.x * 32 + wave * P;   // first pair of this wave

  // A values for this wave's 8 pairs (wave-uniform -> scalar loads)
  float ax[P], ay[P];
#pragma unroll
  for (int i = 0; i < P; ++i) {
    const float2 a = ((const float2*)A)[p_base + i];
    ax[i] = a.x; ay[i] = a.y;
  }

  const float4* __restrict__ B0 = (const float4*)B;         // B[0,0,:]
  const float4* __restrict__ B1 = (const float4*)(B + FF);  // B[0,1,:]

  float m[P];
#pragma unroll
  for (int i = 0; i < P; ++i) m[i] = 3.4e38f;

  // lanes stripe f in float4 chunks: 64 lanes * 4 = 256 f per iter, 8 iters
#pragma unroll
  for (int it = 0; it < FF / 256; ++it) {
    const int idx = it * 64 + lane;
    const float4 b0 = B0[idx];
    const float4 b1 = B1[idx];
#pragma unroll
    for (int i = 0; i < P; ++i) {
      // abs folds into v_max_f32 input mods; min chain folds into v_min3_f32
      const float v0 = fmaxf(fabsf(ax[i] - b0.x), fabsf(ay[i] - b1.x));
      const float v1 = fmaxf(fabsf(ax[i] - b0.y), fabsf(ay[i] - b1.y));
      const float v2 = fmaxf(fabsf(ax[i] - b0.z), fabsf(ay[i] - b1.z));
      const float v3 = fmaxf(fabsf(ax[i] - b0.w), fabsf(ay[i] - b1.w));
      m[i] = fminf(m[i], fminf(fminf(fminf(v0, v1), v2), v3));
    }
  }

  // per-pair min over f (cross-lane), then max over this wave's 8 pairs
  float t = 0.0f;
#pragma unroll
  for (int i = 0; i < P; ++i) {
#pragma unroll
    for (int off = 32; off; off >>= 1)
      m[i] = fminf(m[i], __shfl_xor(m[i], off));
    t = fmaxf(t, m[i]);
  }

  __shared__ float sm[4];
  __shared__ int is_last;
  if (lane == 0) sm[wave] = t;
  __syncthreads();

  if (threadIdx.x == 0) {
    ws[blockIdx.x] = fmaxf(fmaxf(sm[0], sm[1]), fmaxf(sm[2], sm[3]));
    __threadfence();                            // release: ws store visible device-wide
    const unsigned old = atomicAdd(cnt, 1u);    // device-scope by default
    // poison 0xAAAAAAAA; each launch adds exactly 1024 -> residue-keyed last test
    is_last = ((old & (NBLK - 1)) == ((0xAAAAAAAAu + NBLK - 1u) & (NBLK - 1)));
  }
  __syncthreads();

  if (is_last && threadIdx.x < NN) {
    __threadfence();                            // acquire side
    const int n = threadIdx.x;
    float tb = 0.0f;
#pragma unroll
    for (int j = 0; j < NBLK / NN; ++j)         // 16 partials per n
      tb = fmaxf(tb, __hip_atomic_load(&ws[n * (NBLK / NN) + j],
                                       __ATOMIC_RELAXED, __HIP_MEMORY_SCOPE_AGENT));
    out[n] = (1.0f / (1.0f + expf(-10.0f * tb))) *
             (1.0f / (1.0f + expf( 10.0f * tb)));
  }
}

extern "C" void kernel_launch(void* const* d_in, const int* in_sizes, int n_in,
                              void* d_out, int out_size, void* d_ws, size_t ws_size,
                              hipStream_t stream) {
  const float* A = (const float*)d_in[0];   // (64,512,2)
  const float* B = (const float*)d_in[1];   // (1,2,2048)
  float* out     = (float*)d_out;           // (64,1)
  float* ws      = (float*)d_ws;            // [0..1023]: block partials
  unsigned* cnt  = (unsigned*)d_ws + NBLK;  // arrival counter (poison-seeded)

  psl_fused_kernel<<<NBLK, 256, 0, stream>>>(A, B, out, ws, cnt);
}

// Round 5
// 63.389 us; speedup vs baseline: 1.2225x; 1.2225x over previous
//
#include <hip/hip_runtime.h>
#include <hip/hip_bf16.h>

// out[n] = bump( max_l min_f max_c |A[n,l,c] - B[c,f]| ),  bump(x)=sigmoid(10x)*sigmoid(-10x)
// bump strictly decreasing for x>=0  =>  reduce t = max first, bump once at the end.
// N=64, L=512, F=2048.  A:(64,512,2) f32, B:(1,2,2048) f32, out:(64,1) f32.
//
// Two dispatches, no atomics, no fences. R4 post-mortem: single-dispatch fusion
// with device-scope fences cost +15us (1024 blocks x L2-writeback on
// non-coherent per-XCD L2s); inter-kernel ordering is cheaper.

#define NN 64
#define LL 512
#define FF 2048
#define P  8   // pairs per wave (lanes stripe f)

// kernel 1: 1024 blocks x 256 threads; block b owns pairs [32b, 32b+32);
// 16 blocks per n. Writes block max-of-min to ws[b] unconditionally (no init needed).
__global__ __launch_bounds__(256) void psl_reduce_kernel(
    const float* __restrict__ A, const float* __restrict__ B,
    float* __restrict__ ws) {
  const int wave = __builtin_amdgcn_readfirstlane(threadIdx.x >> 6);
  const int lane = threadIdx.x & 63;
  const int p_base = blockIdx.x * 32 + wave * P;   // first pair of this wave

  // A values for this wave's 8 pairs (wave-uniform -> scalar loads)
  float ax[P], ay[P];
#pragma unroll
  for (int i = 0; i < P; ++i) {
    const float2 a = ((const float2*)A)[p_base + i];
    ax[i] = a.x; ay[i] = a.y;
  }

  const float4* __restrict__ B0 = (const float4*)B;         // B[0,0,:]
  const float4* __restrict__ B1 = (const float4*)(B + FF);  // B[0,1,:]

  float m[P];
#pragma unroll
  for (int i = 0; i < P; ++i) m[i] = 3.4e38f;

  // lanes stripe f in float4 chunks: 64 lanes * 4 = 256 f per iter, 8 iters
#pragma unroll
  for (int it = 0; it < FF / 256; ++it) {
    const int idx = it * 64 + lane;
    const float4 b0 = B0[idx];
    const float4 b1 = B1[idx];
#pragma unroll
    for (int i = 0; i < P; ++i) {
      // abs folds into v_max_f32 input mods; min chain folds into v_min3_f32
      const float v0 = fmaxf(fabsf(ax[i] - b0.x), fabsf(ay[i] - b1.x));
      const float v1 = fmaxf(fabsf(ax[i] - b0.y), fabsf(ay[i] - b1.y));
      const float v2 = fmaxf(fabsf(ax[i] - b0.z), fabsf(ay[i] - b1.z));
      const float v3 = fmaxf(fabsf(ax[i] - b0.w), fabsf(ay[i] - b1.w));
      m[i] = fminf(m[i], fminf(fminf(fminf(v0, v1), v2), v3));
    }
  }

  // per-pair min over f (cross-lane), then max over this wave's 8 pairs
  float t = 0.0f;
#pragma unroll
  for (int i = 0; i < P; ++i) {
#pragma unroll
    for (int off = 32; off; off >>= 1)
      m[i] = fminf(m[i], __shfl_xor(m[i], off));
    t = fmaxf(t, m[i]);
  }

  __shared__ float sm[4];
  if (lane == 0) sm[wave] = t;
  __syncthreads();
  if (threadIdx.x == 0)
    ws[blockIdx.x] = fmaxf(fmaxf(sm[0], sm[1]), fmaxf(sm[2], sm[3]));
}

// kernel 2: 1 block x 64 threads; thread n maxes its 16 block results, bumps, stores.
__global__ __launch_bounds__(64) void psl_finalize_kernel(
    const float* __restrict__ ws, float* __restrict__ out) {
  const int n = threadIdx.x;
  float t = 0.0f;
#pragma unroll
  for (int j = 0; j < (LL / 32); ++j)       // 16 blocks per n
    t = fmaxf(t, ws[n * (LL / 32) + j]);
  out[n] = (1.0f / (1.0f + expf(-10.0f * t))) *
           (1.0f / (1.0f + expf( 10.0f * t)));
}

extern "C" void kernel_launch(void* const* d_in, const int* in_sizes, int n_in,
                              void* d_out, int out_size, void* d_ws, size_t ws_size,
                              hipStream_t stream) {
  const float* A = (const float*)d_in[0];   // (64,512,2)
  const float* B = (const float*)d_in[1];   // (1,2,2048)
  float* out     = (float*)d_out;           // (64,1)
  float* ws      = (float*)d_ws;            // 1024 block results

  const int blocks = (NN * LL) / 32;        // 1024
  psl_reduce_kernel<<<blocks, 256, 0, stream>>>(A, B, ws);
  psl_finalize_kernel<<<1, 64, 0, stream>>>(ws, out);
}